// Round 11
// baseline (831.529 us; speedup 1.0000x reference)
//
#include <hip/hip_runtime.h>
#include <cstdint>

typedef unsigned short u16;
typedef __attribute__((ext_vector_type(8))) u16 u16x8;
typedef __attribute__((ext_vector_type(4))) u16 u16x4;
typedef __attribute__((ext_vector_type(8))) _Float16 f16x8;
typedef __attribute__((ext_vector_type(4))) float f32x4;

// ---------- helpers ----------
__device__ __forceinline__ u16 f2h(float f) {
  _Float16 h = (_Float16)f;
  return __builtin_bit_cast(u16, h);
}
__device__ __forceinline__ float h2f(u16 b) {
  _Float16 h = __builtin_bit_cast(_Float16, b);
  return (float)h;
}
__device__ __forceinline__ void gll16(const void* g, void* l) {
  auto gp = reinterpret_cast<const __attribute__((address_space(1))) unsigned int*>(
      reinterpret_cast<uintptr_t>(g));
  auto lp = reinterpret_cast<__attribute__((address_space(3))) unsigned int*>(
      reinterpret_cast<uintptr_t>(l));
  __builtin_amdgcn_global_load_lds(gp, lp, 16, 0, 0);
}

// ---------- prep: NCHW fp32 -> padded(34x34) NHWC fp16, both inputs ----------
__global__ __launch_bounds__(256) void pad_both(const float* __restrict__ qsrc,
                                                const float* __restrict__ ssrc,
                                                u16* __restrict__ PQ,
                                                u16* __restrict__ PS) {
  const int gi = blockIdx.x >> 5;
  const int y  = blockIdx.x & 31;
  const float* in;
  u16* outp;
  int img;
  if (gi < 10) { in = qsrc; outp = PQ; img = gi; }
  else         { in = ssrc; outp = PS; img = gi - 10; }
  __shared__ float tile[32][33];
  const int tid = threadIdx.x;
  u16* base = outp + (long)img * 34 * 34 * 1024;
  const u16x8 z8 = {0, 0, 0, 0, 0, 0, 0, 0};
  {
    u16* r = base + (long)(y + 1) * 34 * 1024;
    if (tid < 128) *(u16x8*)&r[tid * 8] = z8;
    else *(u16x8*)&r[33 * 1024 + (tid - 128) * 8] = z8;
  }
  if (y == 0) {
    for (int i = tid * 8; i < 34816; i += 2048) *(u16x8*)&base[i] = z8;
  }
  if (y == 31) {
    u16* r = base + 33L * 34 * 1024;
    for (int i = tid * 8; i < 34816; i += 2048) *(u16x8*)&r[i] = z8;
  }
  const int xi = tid & 31, ci = tid >> 5;
  const int xo = tid >> 3, q = tid & 7;
  const float* ip = in + (long)img * 1048576 + y * 32;
  u16* op = base + ((long)(y + 1) * 34 + 1) * 1024;
  for (int c0 = 0; c0 < 1024; c0 += 32) {
#pragma unroll
    for (int k2 = 0; k2 < 4; k2++)
      tile[k2 * 8 + ci][xi] = ip[(long)(c0 + k2 * 8 + ci) * 1024 + xi];
    __syncthreads();
    u16x4 o4;
#pragma unroll
    for (int r = 0; r < 4; r++) o4[r] = f2h(tile[q * 4 + r][xo]);
    *(u16x4*)&op[(long)xo * 1024 + c0 + q * 4] = o4;
    __syncthreads();
  }
}

// ---------- merged weight prep ----------
// 3x3 weights in CHANNEL-BLOCK-MAJOR, TAP-MINOR k-order:
//   k = cblk*576 + tap*64 + ci   (cblk = c>>6, ci = c&63)
__device__ __forceinline__ void wre3_body(const float* __restrict__ wp,
                                          u16* __restrict__ op, float* buf) {
  for (int i = threadIdx.x; i < 9216; i += 256) buf[i] = wp[i];
  __syncthreads();
  for (int k = threadIdx.x; k < 9216; k += 256) {
    const int cblk = k / 576;
    const int r = k - cblk * 576;
    const int t = r >> 6, ci = r & 63;
    op[k] = f2h(buf[(cblk * 64 + ci) * 9 + t]);
  }
}
__global__ __launch_bounds__(256) void wprep(
    const float* __restrict__ w_sk, const float* __restrict__ w_sv,
    const float* __restrict__ w_qq, const float* __restrict__ w_qk,
    const float* __restrict__ w_cq, u16* __restrict__ WTSK,
    u16* __restrict__ WTSV, u16* __restrict__ WTQQK, u16* __restrict__ WCQ) {
  __shared__ float buf[9216];
  const int b = blockIdx.x;
  if (b < 128) {
    wre3_body(w_sk + (long)b * 9216, WTSK + (long)b * 9216, buf);
  } else if (b < 640) {
    const int oc = b - 128;
    wre3_body(w_sv + (long)oc * 9216, WTSV + (long)oc * 9216, buf);
  } else if (b < 768) {
    const int oc = b - 640;
    wre3_body(w_qq + (long)oc * 9216, WTQQK + (long)oc * 9216, buf);
  } else if (b < 896) {
    const int oc = b - 768;
    wre3_body(w_qk + (long)oc * 9216, WTQQK + (long)(oc + 128) * 9216, buf);
  } else {
    const int i = (b - 896) * 1024 + threadIdx.x * 4;
#pragma unroll
    for (int r = 0; r < 4; r++) WCQ[i + r] = f2h(w_cq[i + r]);
  }
}

// ---------- row-sum kernels (max-free softmax denominators) ----------
__global__ __launch_bounds__(256) void rowsum60(const u16* __restrict__ P,
                                                float* __restrict__ D) {
  const u16* p = P + (long)blockIdx.x * 15360;
  const int tid = threadIdx.x;
  __shared__ float rs[4];
  float s = 0.f;
  for (int i = tid; i < 1920; i += 256) {
    u16x8 v = *(const u16x8*)(p + (i << 3));
#pragma unroll
    for (int j = 0; j < 8; j++) s += h2f(v[j]);
  }
#pragma unroll
  for (int o = 32; o > 0; o >>= 1) s += __shfl_xor(s, o, 64);
  if ((tid & 63) == 0) rs[tid >> 6] = s;
  __syncthreads();
  if (tid == 0) D[blockIdx.x] = rs[0] + rs[1] + rs[2] + rs[3];
}
__global__ __launch_bounds__(256) void rowsum4(const u16* __restrict__ P,
                                               float* __restrict__ D) {
  const u16* p = P + (long)blockIdx.x * 1024;
  const int tid = threadIdx.x;
  __shared__ float rs[4];
  u16x4 v = *(const u16x4*)(p + (tid << 2));
  float s = h2f(v[0]) + h2f(v[1]) + h2f(v[2]) + h2f(v[3]);
#pragma unroll
  for (int o = 32; o > 0; o >>= 1) s += __shfl_xor(s, o, 64);
  if ((tid & 63) == 0) rs[tid >> 6] = s;
  __syncthreads();
  if (tid == 0) D[blockIdx.x] = rs[0] + rs[1] + rs[2] + rs[3];
}

// ---------- split-K reducers ----------
// NEWV f16 = (sum of 8 f16 chunks) / D1[q]
__global__ __launch_bounds__(256) void reduce8h(const u16* __restrict__ part,
                                                const float* __restrict__ D,
                                                u16* __restrict__ o) {
  long j = ((long)blockIdx.x * 256 + threadIdx.x) * 4;
  int b = (int)(j >> 19);
  long i = j & 524287;
  int q = (int)(i & 1023);
  const u16* p = part + (long)b * 4194304 + i;
  float s0 = 0.f, s1 = 0.f, s2 = 0.f, s3 = 0.f;
#pragma unroll
  for (int c = 0; c < 8; c++) {
    u16x4 v = *(const u16x4*)&p[(long)c * 524288];
    s0 += h2f(v[0]); s1 += h2f(v[1]); s2 += h2f(v[2]); s3 += h2f(v[3]);
  }
  f32x4 dv = *(const f32x4*)&D[b * 1024 + q];
  u16x4 o4 = {f2h(s0 / dv[0]), f2h(s1 / dv[1]), f2h(s2 / dv[2]),
              f2h(s3 / dv[3])};
  *(u16x4*)&o[j] = o4;
}
__global__ __launch_bounds__(256) void reduce_sk(const float* __restrict__ part,
                                                 const float* __restrict__ bias,
                                                 u16* __restrict__ o) {
  long i = ((long)blockIdx.x * 256 + threadIdx.x) * 4;
  f32x4 s = *(const f32x4*)&part[i];
  s = s + *(const f32x4*)&part[i + 3932160];
  f32x4 bb = *(const f32x4*)&bias[(int)(i & 127)];
  u16x4 o4;
#pragma unroll
  for (int r = 0; r < 4; r++) o4[r] = f2h(s[r] + bb[r]);
  *(u16x4*)&o[i] = o4;
}
__global__ __launch_bounds__(256) void reduce_qqk(
    const float* __restrict__ part, const float* __restrict__ b_qq,
    const float* __restrict__ b_qk, u16* __restrict__ QQR,
    u16* __restrict__ QKR) {
  long i = ((long)blockIdx.x * 256 + threadIdx.x) * 4;
  const int n = (int)(i >> 8), m = (int)(i & 255);
  f32x4 s = *(const f32x4*)&part[i];
  s = s + *(const f32x4*)&part[i + 2621440];
  const int lo = (m < 128);
  const int mm = m & 127;
  const float* bs = lo ? b_qq : b_qk;
  f32x4 bb = *(const f32x4*)&bs[mm];
  u16* dst = (lo ? QQR : QKR) + (long)n * 128 + mm;
  u16x4 o4;
#pragma unroll
  for (int r = 0; r < 4; r++) o4[r] = f2h(s[r] + bb[r]);
  *(u16x4*)dst = o4;
}

// ---------- 256x256 GEMM: A in LDS (64KB dbuf), B direct global->reg ----------
// B-fragment layout == NHWC global layout: each lane loads its 16B fragment
// from L2 (cblk-major K order keeps per-XCD B slab L2-resident). LDS port
// traffic per tile drops 256KB -> 160KB. One vmcnt(0)+barrier per tile.
__global__ __launch_bounds__(512, 1)
void gemm256(const u16* __restrict__ A, const u16* __restrict__ B,
             const float* __restrict__ bias, u16* __restrict__ out) {
  __shared__ u16 lds[32768];  // A only: 2 x 32KB
  const int tid = threadIdx.x, lane = tid & 63, wave = tid >> 6;
  const int nwg = gridDim.x * gridDim.y;
  int wg = blockIdx.x + gridDim.x * blockIdx.y;
  wg = (wg & 7) * (nwg >> 3) + (wg >> 3);
  const int ntile = wg % gridDim.x;
  const int mtile = wg / gridDim.x;

  const int slog = (lane & 7) ^ ((lane >> 3) & 7);
  const u16* aS[4];
  int aD[4];
#pragma unroll
  for (int j = 0; j < 4; j++) {
    const int r = wave * 32 + j * 8 + (lane >> 3);
    aS[j] = A + (long)(mtile * 256 + r) * 9216 + slog * 8;
    aD[j] = (wave * 32 + j * 8) * 64;
  }

  const int g = lane >> 4, l15 = lane & 15;
  const int wm = wave >> 2, wn = wave & 3;
  int aRow[8], sx[2];
#pragma unroll
  for (int mi = 0; mi < 8; mi++) aRow[mi] = (wm * 128 + mi * 16 + l15) * 64;
#pragma unroll
  for (int ks = 0; ks < 2; ks++) sx[ks] = ((ks * 4 + g) ^ (l15 & 7)) * 8;

  // per-lane B fragment base pointers (pixel + k-group folded in)
  const u16* bped[4];
#pragma unroll
  for (int ni = 0; ni < 4; ni++) {
    const int n = ntile * 256 + wn * 64 + ni * 16 + l15;
    const int img = n >> 10, p = n & 1023;
    const int y = p >> 5, x = p & 31;
    bped[ni] = B + ((long)((img * 34 + y) * 34 + x)) * 1024 + g * 8;
  }

  auto tapoff = [](int kt) {
    const int cblk = kt / 9;
    const int t = kt - cblk * 9;
    const int dy = t / 3, dx = t - dy * 3;
    return (dy * 34 + dx) * 1024 + cblk * 64;
  };

  f32x4 acc[8][4];
  const f32x4 zero = {0.f, 0.f, 0.f, 0.f};
#pragma unroll
  for (int i = 0; i < 8; i++)
#pragma unroll
    for (int j = 0; j < 4; j++) acc[i][j] = zero;

  f16x8 b0X[4], b0Y[4], b1[4], a3[4];
  f16x8 zf;
#pragma unroll
  for (int j = 0; j < 8; j++) zf[j] = (_Float16)0.0f;
#pragma unroll
  for (int i = 0; i < 4; i++) { a3[i] = zf; b1[i] = zf; }

  // prologue: stage A(0) -> buf0, load B ks0 of tile 0 -> b0X
  {
#pragma unroll
    for (int j = 0; j < 4; j++) gll16(aS[j], &lds[aD[j]]);
    const int t0 = tapoff(0);
#pragma unroll
    for (int ni = 0; ni < 4; ni++) b0X[ni] = *(const f16x8*)(bped[ni] + t0);
    asm volatile("s_waitcnt vmcnt(0)" ::: "memory");
    __builtin_amdgcn_s_barrier();
  }

  // tile body: bc = ks0 frags of tile kt (prefetched), bn = storage for kt+1
  auto body = [&](int kt, f16x8 (&bc)[4], f16x8 (&bn)[4]) {
    const int abuf = (kt & 1) << 14;
    const int anbuf = abuf ^ 16384;
    const bool stA = (kt + 1 < 144);
    f16x8 a0[4], a1[4];
    // 1. deferred ph3 of previous tile (zeros at kt==0)
#pragma unroll
    for (int mi = 0; mi < 4; mi++)
#pragma unroll
      for (int ni = 0; ni < 4; ni++)
        acc[mi + 4][ni] = __builtin_amdgcn_mfma_f32_16x16x32_f16(
            a3[mi], b1[ni], acc[mi + 4][ni], 0, 0, 0);
    // 2. stage A(kt+1)
    if (stA) {
      const int kA = (kt + 1) << 6;
#pragma unroll
      for (int j = 0; j < 4; j++) gll16(aS[j] + kA, &lds[anbuf + aD[j]]);
    }
    // 3. load b1 = ks1 of THIS tile; bn = ks0 of NEXT tile
    {
      const int to = tapoff(kt);
#pragma unroll
      for (int ni = 0; ni < 4; ni++)
        b1[ni] = *(const f16x8*)(bped[ni] + to + 32);
      if (stA) {
        const int tn = tapoff(kt + 1);
#pragma unroll
        for (int ni = 0; ni < 4; ni++)
          bn[ni] = *(const f16x8*)(bped[ni] + tn);
      }
    }
    // 4. ph0: rows 0-3 x ks0
#pragma unroll
    for (int i = 0; i < 4; i++) a0[i] = *(const f16x8*)&lds[abuf + aRow[i] + sx[0]];
#pragma unroll
    for (int mi = 0; mi < 4; mi++)
#pragma unroll
      for (int ni = 0; ni < 4; ni++)
        acc[mi][ni] = __builtin_amdgcn_mfma_f32_16x16x32_f16(
            a0[mi], bc[ni], acc[mi][ni], 0, 0, 0);
    // 5. ph1: rows 4-7 x ks0
#pragma unroll
    for (int i = 0; i < 4; i++) a1[i] = *(const f16x8*)&lds[abuf + aRow[i + 4] + sx[0]];
#pragma unroll
    for (int mi = 0; mi < 4; mi++)
#pragma unroll
      for (int ni = 0; ni < 4; ni++)
        acc[mi + 4][ni] = __builtin_amdgcn_mfma_f32_16x16x32_f16(
            a1[mi], bc[ni], acc[mi + 4][ni], 0, 0, 0);
    // 6. ph2: rows 0-3 x ks1
#pragma unroll
    for (int i = 0; i < 4; i++) a0[i] = *(const f16x8*)&lds[abuf + aRow[i] + sx[1]];
#pragma unroll
    for (int mi = 0; mi < 4; mi++)
#pragma unroll
      for (int ni = 0; ni < 4; ni++)
        acc[mi][ni] = __builtin_amdgcn_mfma_f32_16x16x32_f16(
            a0[mi], b1[ni], acc[mi][ni], 0, 0, 0);
    // 7. rows 4-7 ks1 -> a3 (deferred past the barrier)
#pragma unroll
    for (int i = 0; i < 4; i++) a3[i] = *(const f16x8*)&lds[abuf + aRow[i + 4] + sx[1]];
    // 8. tile gate
    asm volatile("s_waitcnt vmcnt(0)" ::: "memory");
    __builtin_amdgcn_s_barrier();
  };

  for (int kt2 = 0; kt2 < 144; kt2 += 2) {
    body(kt2, b0X, b0Y);
    body(kt2 + 1, b0Y, b0X);
  }
  // final deferred ph3 (tile 143)
#pragma unroll
  for (int mi = 0; mi < 4; mi++)
#pragma unroll
    for (int ni = 0; ni < 4; ni++)
      acc[mi + 4][ni] = __builtin_amdgcn_mfma_f32_16x16x32_f16(
          a3[mi], b1[ni], acc[mi + 4][ni], 0, 0, 0);

  // ---- epilogue: SVA[b][m][col] = acc + bias[m] ----
#pragma unroll
  for (int mi = 0; mi < 8; mi++) {
#pragma unroll
    for (int ni = 0; ni < 4; ni++) {
      f32x4 v = acc[mi][ni];
      const int m0 = mtile * 256 + wm * 128 + mi * 16 + g * 4;
      const int n = ntile * 256 + wn * 64 + ni * 16 + l15;
      const int b = (n >= 15360) ? 1 : 0;
      const int rem = n - b * 15360;
#pragma unroll
      for (int r = 0; r < 4; r++) {
        const int m = m0 + r;
        out[(long)b * 7864320 + (long)m * 15360 + rem] = f2h(v[r] + bias[m]);
      }
    }
  }
}

// ---------- 128x128 NT GEMM (2-phase, general purpose) ----------
// EPI: 0 f16 transposed store; 1 f16 row store *scale(+bias); 2 qf fp32;
//      3 final fp32 (/bias2[z*5120+n]); 4 fp32 partial row; 5 fp32 transposed
//      partial; 6 f16 partial row; 7 f16 row store exp(v*scale - cexp)
template <int BMODE, int EPI, int SPLITK>
__global__ __launch_bounds__(256, 2)
void gemm_nt(const u16* __restrict__ A, long Azoff, int Astride,
             const u16* __restrict__ B, long Bzoff, int Bstride,
             int K, float scale,
             const float* __restrict__ bias, const float* __restrict__ bias2,
             void* __restrict__ out0, void* __restrict__ out1,
             long out_zoff, int ldo, float cexp = 0.f) {
  __shared__ u16 lds[4 * 8192];
  const int tid = threadIdx.x;
  const int lane = tid & 63;
  const int wave = tid >> 6;
  const int mtile = blockIdx.y, ntile = blockIdx.x, z = blockIdx.z;

  const int zb = (SPLITK > 1) ? z / SPLITK : z;
  const int zc = (SPLITK > 1) ? z % SPLITK : 0;
  const u16* Ab = A + (long)zb * Azoff + (long)zc * K;
  const u16* Bb = B + (long)zb * Bzoff + ((BMODE == 0) ? (long)zc * K : 0);

  const int r8 = lane >> 3;
  const int sphys = lane & 7;
  const u16* aSrc[4];
  const u16* bSrc[4];
  u16* aDst[4];
  u16* bDst[4];
#pragma unroll
  for (int i = 0; i < 4; i++) {
    const int row = wave * 32 + i * 8 + r8;
    const int slog = sphys ^ (row & 7);
    aSrc[i] = Ab + (long)(mtile * 128 + row) * Astride + slog * 8;
    if (BMODE == 0) {
      bSrc[i] = Bb + (long)(ntile * 128 + row) * Bstride + slog * 8;
    } else {
      const int n = ntile * 128 + row;
      const int img = n >> 10;
      const int p = n & 1023;
      const int y = p >> 5, x = p & 31;
      bSrc[i] = Bb + ((long)(img * 34 + y) * 34 + x) * 1024 + slog * 8;
    }
    aDst[i] = &lds[0] + (wave * 32 + i * 8) * 64;
    bDst[i] = &lds[0] + 8192 + (wave * 32 + i * 8) * 64;
  }

  const int g = lane >> 4, l15 = lane & 15;
  const int wm = wave >> 1, wn = wave & 1;
  int offA[2][4], offB[2][4];
#pragma unroll
  for (int ks = 0; ks < 2; ks++) {
    const int sl = ks * 4 + g;
#pragma unroll
    for (int i = 0; i < 4; i++) {
      const int ra = wm * 64 + i * 16 + l15;
      offA[ks][i] = ra * 64 + ((sl ^ (ra & 7)) * 8);
      const int rb = wn * 64 + i * 16 + l15;
      offB[ks][i] = 8192 + rb * 64 + ((sl ^ (rb & 7)) * 8);
    }
  }

  auto stage = [&](int buf, int kb) {
    int bAdd;
    if (BMODE == 0) {
      bAdd = kb;
    } else if (BMODE == 1) {
      const int ktg = (zc * K + kb) >> 6;
      const int cblk = ktg / 9;
      const int t = ktg - cblk * 9;
      const int dy = t / 3, dx = t - dy * 3;
      bAdd = (dy * 34 + dx) * 1024 + cblk * 64;
    } else {
      bAdd = 35 * 1024 + kb;
    }
    const int bufo = buf * 16384;
#pragma unroll
    for (int i = 0; i < 4; i++) gll16(aSrc[i] + kb, aDst[i] + bufo);
#pragma unroll
    for (int i = 0; i < 4; i++) gll16(bSrc[i] + bAdd, bDst[i] + bufo);
  };

  f32x4 acc[4][4];
  const f32x4 zero = {0.f, 0.f, 0.f, 0.f};
#pragma unroll
  for (int i = 0; i < 4; i++)
#pragma unroll
    for (int j = 0; j < 4; j++) acc[i][j] = zero;

  const int nkt = K >> 6;
  stage(0, 0);
  __syncthreads();
  for (int kt = 0; kt < nkt; ++kt) {
    const int buf = kt & 1;
    if (kt + 1 < nkt) stage(buf ^ 1, (kt + 1) << 6);
#pragma unroll
    for (int ks = 0; ks < 2; ks++) {
      f16x8 af[4], bfg[4];
#pragma unroll
      for (int i = 0; i < 4; i++)
        af[i] = *(const f16x8*)&lds[buf * 16384 + offA[ks][i]];
#pragma unroll
      for (int i = 0; i < 4; i++)
        bfg[i] = *(const f16x8*)&lds[buf * 16384 + offB[ks][i]];
#pragma unroll
      for (int mi = 0; mi < 4; mi++)
#pragma unroll
        for (int ni = 0; ni < 4; ni++)
          acc[mi][ni] = __builtin_amdgcn_mfma_f32_16x16x32_f16(
              af[mi], bfg[ni], acc[mi][ni], 0, 0, 0);
    }
    __syncthreads();
  }

#pragma unroll
  for (int mi = 0; mi < 4; mi++) {
#pragma unroll
    for (int ni = 0; ni < 4; ni++) {
      f32x4 v = acc[mi][ni];
      const int m0 = mtile * 128 + wm * 64 + mi * 16 + g * 4;
      const int n = ntile * 128 + wn * 64 + ni * 16 + l15;
      if (EPI == 0) {
        u16* ob = (u16*)out0;
        const float* bs = bias;
        int mm = m0;
        if (out1 != nullptr && m0 >= 128) { ob = (u16*)out1; bs = bias2; mm = m0 - 128; }
        u16x4 pk;
#pragma unroll
        for (int r = 0; r < 4; r++) {
          float val = v[r] * scale + (bs ? bs[mm + r] : 0.f);
          pk[r] = f2h(val);
        }
        *(u16x4*)&ob[(long)n * ldo + mm] = pk;
      } else if (EPI == 1) {
        u16* ob = (u16*)out0 + (long)z * out_zoff;
#pragma unroll
        for (int r = 0; r < 4; r++) {
          const int m = m0 + r;
          float val = v[r] * scale + (bias ? bias[m] : 0.f);
          ob[(long)m * ldo + n] = f2h(val);
        }
      } else if (EPI == 2) {
        float* of = (float*)out0;
        const int img = n >> 10, p = n & 1023;
#pragma unroll
        for (int r = 0; r < 4; r++) {
          const int m = m0 + r;
          of[(long)img * 1048576 + (long)(512 + m) * 1024 + p] =
              v[r] + (bias ? bias[m] : 0.f);
        }
      } else if (EPI == 3) {
        float* of = (float*)out0;
        const int f = n >> 10, p = n & 1023;
        const float dinv = 1.0f / bias2[(long)z * 5120 + n];
#pragma unroll
        for (int r = 0; r < 4; r++) {
          const int m = m0 + r;
          of[(long)z * 5242880 + (long)f * 1048576 + (long)m * 1024 + p] =
              v[r] * dinv;
        }
      } else if (EPI == 4) {
        float* of = (float*)out0 + (long)z * out_zoff;
#pragma unroll
        for (int r = 0; r < 4; r++) of[(long)(m0 + r) * ldo + n] = v[r];
      } else if (EPI == 5) {
        float* of = (float*)out0 + (long)zc * out_zoff;
        *(f32x4*)&of[(long)n * ldo + m0] = v;
      } else if (EPI == 6) {
        u16* ob = (u16*)out0 + (long)z * out_zoff;
#pragma unroll
        for (int r = 0; r < 4; r++) ob[(long)(m0 + r) * ldo + n] = f2h(v[r]);
      } else {  // EPI == 7: f16 row store of exp(v*scale - cexp)
        u16* ob = (u16*)out0 + (long)z * out_zoff;
#pragma unroll
        for (int r = 0; r < 4; r++) {
          const int m = m0 + r;
          ob[(long)m * ldo + n] = f2h(__expf(v[r] * scale - cexp));
        }
      }
    }
  }
}

// ---------- launch ----------
extern "C" void kernel_launch(void* const* d_in, const int* in_sizes, int n_in,
                              void* d_out, int out_size, void* d_ws, size_t ws_size,
                              hipStream_t stream) {
  (void)in_sizes; (void)n_in; (void)out_size;
  const float* query   = (const float*)d_in[0];
  const float* support = (const float*)d_in[1];
  const float* w_sk = (const float*)d_in[2];  const float* b_sk = (const float*)d_in[3];
  const float* w_sv = (const float*)d_in[4];  const float* b_sv = (const float*)d_in[5];
  const float* w_qq = (const float*)d_in[6];  const float* b_qq = (const float*)d_in[7];
  const float* w_qk = (const float*)d_in[8];  const float* b_qk = (const float*)d_in[9];
  const float* w_cq = (const float*)d_in[10]; const float* b_cq = (const float*)d_in[11];
  float* out = (float*)d_out;
  char* ws = (char*)d_ws;

  if (ws_size < 158924800u) return;

  u16* PQ    = (u16*)(ws + 0);
  u16* PS    = (u16*)(ws + 23674880);
  u16* WTSK  = (u16*)(ws + 94699520);
  u16* WTSV  = (u16*)(ws + 97058816);
  u16* WTQQK = (u16*)(ws + 106496000);
  u16* WCQ   = (u16*)(ws + 111214592);
  u16* SKR   = (u16*)(ws + 112263168);
  u16* SVA   = (u16*)(ws + 120127488);
  u16* QQR   = (u16*)(ws + 151584768);
  u16* QKR   = (u16*)(ws + 154206208);
  u16* NEWV  = (u16*)(ws + 156827648);
  u16* P1T   = PS;                       // alias (PS dead after sv conv)
  u16* P2T   = PQ;                       // alias (PQ dead after qqk/qf convs)
  u16* PART2 = (u16*)(ws + 94699520);    // over weights: [16][512][1024] f16
  float* PARTK = (float*)SVA;            // pre-sv aliases
  float* PARTQ = (float*)SVA;
  float* D1 = (float*)(ws + 112263168);  // over SKR (dead after P1 gemm)
  float* D2 = D1 + 2048;

  const float SCALE = 0.08838834764831843f;  // 1/sqrt(128)

  pad_both<<<dim3(1280), 256, 0, stream>>>(query, support, PQ, PS);
  wprep<<<dim3(1408), 256, 0, stream>>>(w_sk, w_sv, w_qq, w_qk, w_cq,
                                        WTSK, WTSV, WTQQK, WCQ);

  // sk conv: split-K=2 -> fp32 partials, then reduce(+bias)
  gemm_nt<1, 5, 2><<<dim3(240, 1, 2), 256, 0, stream>>>(
      WTSK, 0, 9216, PS, 0, 0, 4608, 1.0f, nullptr, nullptr, PARTK, nullptr,
      3932160L, 128);
  reduce_sk<<<dim3(3840), 256, 0, stream>>>(PARTK, b_sk, SKR);

  // qq+qk conv: split-K=2 -> fp32 partials, then reduce(+bias)
  gemm_nt<1, 5, 2><<<dim3(80, 2, 2), 256, 0, stream>>>(
      WTQQK, 0, 9216, PQ, 0, 0, 4608, 1.0f, nullptr, nullptr, PARTQ, nullptr,
      2621440L, 256);
  reduce_qqk<<<dim3(2560), 256, 0, stream>>>(PARTQ, b_qq, b_qk, QQR, QKR);

  // sv conv
  gemm256<<<dim3(120, 2), 512, 0, stream>>>(WTSV, PS, b_sv, SVA);

  // qf 1x1 conv
  gemm_nt<2, 2, 1><<<dim3(80, 4, 1), 256, 0, stream>>>(
      WCQ, 0, 1024, PQ, 0, 0, 1024, 1.0f, b_cq, nullptr, out, nullptr, 0, 0);

  // stage 1: P1hat = exp(QK/sqrt(d) - 12), rowsum D1, newV = SV*P1hat / D1
  gemm_nt<0, 7, 1><<<dim3(120, 8, 2), 256, 0, stream>>>(
      QQR + 262144, 655360L, 128, SKR, 1966080L, 128, 128, SCALE, nullptr,
      nullptr, P1T, nullptr, 15728640L, 15360, 12.0f);
  rowsum60<<<dim3(2048), 256, 0, stream>>>(P1T, D1);
  gemm_nt<0, 6, 8><<<dim3(8, 4, 16), 256, 0, stream>>>(
      SVA, 7864320L, 15360, P1T, 15728640L, 15360, 1920, 1.0f, nullptr,
      nullptr, PART2, nullptr, 524288L, 1024);
  reduce8h<<<dim3(1024), 256, 0, stream>>>(PART2, D1, NEWV);

  // stage 2: P2hat = exp(QK/sqrt(d) - 10), rowsum D2, Out = newV*P2hat / D2
  gemm_nt<0, 7, 1><<<dim3(8, 40, 2), 256, 0, stream>>>(
      QQR, 655360L, 128, QKR + 262144, 655360L, 128, 128, SCALE, nullptr,
      nullptr, P2T, nullptr, 5242880L, 1024, 10.0f);
  rowsum4<<<dim3(10240), 256, 0, stream>>>(P2T, D2);
  gemm_nt<0, 3, 1><<<dim3(40, 4, 2), 256, 0, stream>>>(
      NEWV, 524288L, 1024, P2T, 5242880L, 1024, 1024, 1.0f, nullptr, D2,
      out, nullptr, 0, 0);
}

// Round 12
// 595.484 us; speedup vs baseline: 1.3964x; 1.3964x over previous
//
#include <hip/hip_runtime.h>
#include <cstdint>

typedef unsigned short u16;
typedef __attribute__((ext_vector_type(8))) u16 u16x8;
typedef __attribute__((ext_vector_type(4))) u16 u16x4;
typedef __attribute__((ext_vector_type(8))) _Float16 f16x8;
typedef __attribute__((ext_vector_type(4))) float f32x4;

// ---------- helpers ----------
__device__ __forceinline__ u16 f2h(float f) {
  _Float16 h = (_Float16)f;
  return __builtin_bit_cast(u16, h);
}
__device__ __forceinline__ float h2f(u16 b) {
  _Float16 h = __builtin_bit_cast(_Float16, b);
  return (float)h;
}
__device__ __forceinline__ void gll16(const void* g, void* l) {
  auto gp = reinterpret_cast<const __attribute__((address_space(1))) unsigned int*>(
      reinterpret_cast<uintptr_t>(g));
  auto lp = reinterpret_cast<__attribute__((address_space(3))) unsigned int*>(
      reinterpret_cast<uintptr_t>(l));
  __builtin_amdgcn_global_load_lds(gp, lp, 16, 0, 0);
}

// ---------- prep: NCHW fp32 -> padded(34x34) NHWC fp16, both inputs ----------
__global__ __launch_bounds__(256) void pad_both(const float* __restrict__ qsrc,
                                                const float* __restrict__ ssrc,
                                                u16* __restrict__ PQ,
                                                u16* __restrict__ PS) {
  const int gi = blockIdx.x >> 5;
  const int y  = blockIdx.x & 31;
  const float* in;
  u16* outp;
  int img;
  if (gi < 10) { in = qsrc; outp = PQ; img = gi; }
  else         { in = ssrc; outp = PS; img = gi - 10; }
  __shared__ float tile[32][33];
  const int tid = threadIdx.x;
  u16* base = outp + (long)img * 34 * 34 * 1024;
  const u16x8 z8 = {0, 0, 0, 0, 0, 0, 0, 0};
  {
    u16* r = base + (long)(y + 1) * 34 * 1024;
    if (tid < 128) *(u16x8*)&r[tid * 8] = z8;
    else *(u16x8*)&r[33 * 1024 + (tid - 128) * 8] = z8;
  }
  if (y == 0) {
    for (int i = tid * 8; i < 34816; i += 2048) *(u16x8*)&base[i] = z8;
  }
  if (y == 31) {
    u16* r = base + 33L * 34 * 1024;
    for (int i = tid * 8; i < 34816; i += 2048) *(u16x8*)&r[i] = z8;
  }
  const int xi = tid & 31, ci = tid >> 5;
  const int xo = tid >> 3, q = tid & 7;
  const float* ip = in + (long)img * 1048576 + y * 32;
  u16* op = base + ((long)(y + 1) * 34 + 1) * 1024;
  for (int c0 = 0; c0 < 1024; c0 += 32) {
#pragma unroll
    for (int k2 = 0; k2 < 4; k2++)
      tile[k2 * 8 + ci][xi] = ip[(long)(c0 + k2 * 8 + ci) * 1024 + xi];
    __syncthreads();
    u16x4 o4;
#pragma unroll
    for (int r = 0; r < 4; r++) o4[r] = f2h(tile[q * 4 + r][xo]);
    *(u16x4*)&op[(long)xo * 1024 + c0 + q * 4] = o4;
    __syncthreads();
  }
}

// ---------- merged weight prep ----------
// 3x3 weights in CHANNEL-BLOCK-MAJOR, TAP-MINOR k-order:
//   k = cblk*576 + tap*64 + ci   (cblk = c>>6, ci = c&63)
__device__ __forceinline__ void wre3_body(const float* __restrict__ wp,
                                          u16* __restrict__ op, float* buf) {
  for (int i = threadIdx.x; i < 9216; i += 256) buf[i] = wp[i];
  __syncthreads();
  for (int k = threadIdx.x; k < 9216; k += 256) {
    const int cblk = k / 576;
    const int r = k - cblk * 576;
    const int t = r >> 6, ci = r & 63;
    op[k] = f2h(buf[(cblk * 64 + ci) * 9 + t]);
  }
}
__global__ __launch_bounds__(256) void wprep(
    const float* __restrict__ w_sk, const float* __restrict__ w_sv,
    const float* __restrict__ w_qq, const float* __restrict__ w_qk,
    const float* __restrict__ w_cq, u16* __restrict__ WTSK,
    u16* __restrict__ WTSV, u16* __restrict__ WTQQK, u16* __restrict__ WCQ) {
  __shared__ float buf[9216];
  const int b = blockIdx.x;
  if (b < 128) {
    wre3_body(w_sk + (long)b * 9216, WTSK + (long)b * 9216, buf);
  } else if (b < 640) {
    const int oc = b - 128;
    wre3_body(w_sv + (long)oc * 9216, WTSV + (long)oc * 9216, buf);
  } else if (b < 768) {
    const int oc = b - 640;
    wre3_body(w_qq + (long)oc * 9216, WTQQK + (long)oc * 9216, buf);
  } else if (b < 896) {
    const int oc = b - 768;
    wre3_body(w_qk + (long)oc * 9216, WTQQK + (long)(oc + 128) * 9216, buf);
  } else {
    const int i = (b - 896) * 1024 + threadIdx.x * 4;
#pragma unroll
    for (int r = 0; r < 4; r++) WCQ[i + r] = f2h(w_cq[i + r]);
  }
}

// ---------- final denominator reduce: D[row] = sum_{t<NT} PS[row*NT+t] ----
__global__ __launch_bounds__(64) void reduceD(const float* __restrict__ ps,
                                              float* __restrict__ D, int NT) {
  const int row = blockIdx.x, tid = threadIdx.x;
  const float* p = ps + (long)row * NT;
  float s = (tid < NT) ? p[tid] : 0.f;
  if (tid + 64 < NT) s += p[tid + 64];
#pragma unroll
  for (int o = 32; o > 0; o >>= 1) s += __shfl_xor(s, o, 64);
  if (tid == 0) D[row] = s;
}

// ---------- split-K reducers ----------
// NEWV f16 = (sum of 8 f16 chunks) / D1[q]
__global__ __launch_bounds__(256) void reduce8h(const u16* __restrict__ part,
                                                const float* __restrict__ D,
                                                u16* __restrict__ o) {
  long j = ((long)blockIdx.x * 256 + threadIdx.x) * 4;
  int b = (int)(j >> 19);
  long i = j & 524287;
  int q = (int)(i & 1023);
  const u16* p = part + (long)b * 4194304 + i;
  float s0 = 0.f, s1 = 0.f, s2 = 0.f, s3 = 0.f;
#pragma unroll
  for (int c = 0; c < 8; c++) {
    u16x4 v = *(const u16x4*)&p[(long)c * 524288];
    s0 += h2f(v[0]); s1 += h2f(v[1]); s2 += h2f(v[2]); s3 += h2f(v[3]);
  }
  f32x4 dv = *(const f32x4*)&D[b * 1024 + q];
  u16x4 o4 = {f2h(s0 / dv[0]), f2h(s1 / dv[1]), f2h(s2 / dv[2]),
              f2h(s3 / dv[3])};
  *(u16x4*)&o[j] = o4;
}
// SKR[n][128] = part0 + part1 (f16 halves) + bias[m]
__global__ __launch_bounds__(256) void reduce_sk(const u16* __restrict__ part,
                                                 const float* __restrict__ bias,
                                                 u16* __restrict__ o) {
  long i = ((long)blockIdx.x * 256 + threadIdx.x) * 4;
  u16x4 a = *(const u16x4*)&part[i];
  u16x4 b = *(const u16x4*)&part[i + 3932160];
  f32x4 bb = *(const f32x4*)&bias[(int)(i & 127)];
  u16x4 o4;
#pragma unroll
  for (int r = 0; r < 4; r++) o4[r] = f2h(h2f(a[r]) + h2f(b[r]) + bb[r]);
  *(u16x4*)&o[i] = o4;
}
// QQR/QKR from f16 partial halves + bias
__global__ __launch_bounds__(256) void reduce_qqk(
    const u16* __restrict__ part, const float* __restrict__ b_qq,
    const float* __restrict__ b_qk, u16* __restrict__ QQR,
    u16* __restrict__ QKR) {
  long i = ((long)blockIdx.x * 256 + threadIdx.x) * 4;
  const int n = (int)(i >> 8), m = (int)(i & 255);
  u16x4 a = *(const u16x4*)&part[i];
  u16x4 b = *(const u16x4*)&part[i + 2621440];
  const int lo = (m < 128);
  const int mm = m & 127;
  const float* bs = lo ? b_qq : b_qk;
  f32x4 bb = *(const f32x4*)&bs[mm];
  u16* dst = (lo ? QQR : QKR) + (long)n * 128 + mm;
  u16x4 o4;
#pragma unroll
  for (int r = 0; r < 4; r++) o4[r] = f2h(h2f(a[r]) + h2f(b[r]) + bb[r]);
  *(u16x4*)dst = o4;
}

// ---------- 256x256 GEMM, barrier-free K-tile interior (r8/r10 proven) ----
__global__ __launch_bounds__(512, 1)
void gemm256(const u16* __restrict__ A, const u16* __restrict__ B,
             const float* __restrict__ bias, u16* __restrict__ out) {
  __shared__ u16 lds[81920];  // A: 2x32KB @0, B: 3x32KB @32768(u16)
  const int tid = threadIdx.x, lane = tid & 63, wave = tid >> 6;
  const int nwg = gridDim.x * gridDim.y;
  int wg = blockIdx.x + gridDim.x * blockIdx.y;
  wg = (wg & 7) * (nwg >> 3) + (wg >> 3);
  const int ntile = wg % gridDim.x;
  const int mtile = wg / gridDim.x;

  const int slog = (lane & 7) ^ ((lane >> 3) & 7);
  const u16* aS[4];
  const u16* bS[4];
  int aD[4], bD[4];
#pragma unroll
  for (int j = 0; j < 4; j++) {
    const int r = wave * 32 + j * 8 + (lane >> 3);
    aS[j] = A + (long)(mtile * 256 + r) * 9216 + slog * 8;
    aD[j] = (wave * 32 + j * 8) * 64;
    const int n = ntile * 256 + r;
    const int img = n >> 10, p = n & 1023;
    const int y = p >> 5, x = p & 31;
    bS[j] = B + ((long)((img * 34 + y) * 34 + x)) * 1024 + slog * 8;
    bD[j] = (wave * 32 + j * 8) * 64;
  }

  const int g = lane >> 4, l15 = lane & 15;
  const int wm = wave >> 2, wn = wave & 3;
  int aRow[8], bRow[4], sx[2];
#pragma unroll
  for (int mi = 0; mi < 8; mi++) aRow[mi] = (wm * 128 + mi * 16 + l15) * 64;
#pragma unroll
  for (int ni = 0; ni < 4; ni++) bRow[ni] = (wn * 64 + ni * 16 + l15) * 64;
#pragma unroll
  for (int ks = 0; ks < 2; ks++) sx[ks] = ((ks * 4 + g) ^ (l15 & 7)) * 8;

  auto conv_badd = [](int kt) {
    const int cblk = kt / 9;
    const int t = kt - cblk * 9;
    const int dy = t / 3, dx = t - dy * 3;
    return (dy * 34 + dx) * 1024 + cblk * 64;
  };

  f32x4 acc[8][4];
  const f32x4 zero = {0.f, 0.f, 0.f, 0.f};
#pragma unroll
  for (int i = 0; i < 8; i++)
#pragma unroll
    for (int j = 0; j < 4; j++) acc[i][j] = zero;

  const int nkt = 144;
  {
#pragma unroll
    for (int j = 0; j < 4; j++) gll16(aS[j], &lds[aD[j]]);
    const int b0o = conv_badd(0), b1o = conv_badd(1);
#pragma unroll
    for (int j = 0; j < 4; j++) gll16(bS[j] + b0o, &lds[32768 + bD[j]]);
#pragma unroll
    for (int j = 0; j < 4; j++) gll16(bS[j] + b1o, &lds[49152 + bD[j]]);
    asm volatile("s_waitcnt vmcnt(4)" ::: "memory");
    __builtin_amdgcn_s_barrier();
  }

  f16x8 a0[4], a1[4], a3[4], b0[4], b2[4];
  f16x8 zf;
#pragma unroll
  for (int j = 0; j < 8; j++) zf[j] = (_Float16)0.0f;
#pragma unroll
  for (int i = 0; i < 4; i++) { a3[i] = zf; b2[i] = zf; }

  int bc = 0;
  for (int kt = 0; kt < nkt; ++kt) {
    const int abuf = (kt & 1) << 14;
    const int anbuf = abuf ^ 16384;
    const int bbuf = 32768 + bc * 16384;
    int bsn = bc + 2; if (bsn >= 3) bsn -= 3;
    const int bnbuf = 32768 + bsn * 16384;
    const bool stA = (kt + 1 < nkt);
    const bool stB = (kt + 2 < nkt);
    const int kA = (kt + 1) << 6;
    const int bAdd2 = stB ? conv_badd(kt + 2) : 0;

    // L0: ks0 fragments
#pragma unroll
    for (int i = 0; i < 4; i++) a0[i] = *(const f16x8*)&lds[abuf + aRow[i] + sx[0]];
#pragma unroll
    for (int i = 0; i < 4; i++) b0[i] = *(const f16x8*)&lds[bbuf + bRow[i] + sx[0]];
#pragma unroll
    for (int i = 0; i < 4; i++) a1[i] = *(const f16x8*)&lds[abuf + aRow[i + 4] + sx[0]];
    // deferred ph3 of previous tile (zeros on kt==0)
#pragma unroll
    for (int mi = 0; mi < 4; mi++)
#pragma unroll
      for (int ni = 0; ni < 4; ni++)
        acc[mi + 4][ni] = __builtin_amdgcn_mfma_f32_16x16x32_f16(
            a3[mi], b2[ni], acc[mi + 4][ni], 0, 0, 0);
    if (stA) {
#pragma unroll
      for (int j = 0; j < 4; j++) gll16(aS[j] + kA, &lds[anbuf + aD[j]]);
    }
    // ph0
#pragma unroll
    for (int mi = 0; mi < 4; mi++)
#pragma unroll
      for (int ni = 0; ni < 4; ni++)
        acc[mi][ni] = __builtin_amdgcn_mfma_f32_16x16x32_f16(
            a0[mi], b0[ni], acc[mi][ni], 0, 0, 0);
    // L1: ks1 rows 0-3 + B ks1
#pragma unroll
    for (int i = 0; i < 4; i++) a0[i] = *(const f16x8*)&lds[abuf + aRow[i] + sx[1]];
#pragma unroll
    for (int i = 0; i < 4; i++) b2[i] = *(const f16x8*)&lds[bbuf + bRow[i] + sx[1]];
    if (stB) {
#pragma unroll
      for (int j = 0; j < 4; j++) gll16(bS[j] + bAdd2, &lds[bnbuf + bD[j]]);
    }
    // ph1
#pragma unroll
    for (int mi = 0; mi < 4; mi++)
#pragma unroll
      for (int ni = 0; ni < 4; ni++)
        acc[mi + 4][ni] = __builtin_amdgcn_mfma_f32_16x16x32_f16(
            a1[mi], b0[ni], acc[mi + 4][ni], 0, 0, 0);
    // L2: ks1 rows 4-7 (feeds deferred ph3 next tile)
#pragma unroll
    for (int i = 0; i < 4; i++) a3[i] = *(const f16x8*)&lds[abuf + aRow[i + 4] + sx[1]];
    // ph2
#pragma unroll
    for (int mi = 0; mi < 4; mi++)
#pragma unroll
      for (int ni = 0; ni < 4; ni++)
        acc[mi][ni] = __builtin_amdgcn_mfma_f32_16x16x32_f16(
            a0[mi], b2[ni], acc[mi][ni], 0, 0, 0);
    if (stB) {
      asm volatile("s_waitcnt vmcnt(4)" ::: "memory");
    } else if (stA) {
      asm volatile("s_waitcnt vmcnt(0)" ::: "memory");
    }
    __builtin_amdgcn_s_barrier();
    bc = bc + 1; if (bc >= 3) bc -= 3;
  }
  // final deferred ph3
#pragma unroll
  for (int mi = 0; mi < 4; mi++)
#pragma unroll
    for (int ni = 0; ni < 4; ni++)
      acc[mi + 4][ni] = __builtin_amdgcn_mfma_f32_16x16x32_f16(
          a3[mi], b2[ni], acc[mi + 4][ni], 0, 0, 0);

  // ---- epilogue: SVA[b][m][col] = acc + bias[m] ----
#pragma unroll
  for (int mi = 0; mi < 8; mi++) {
#pragma unroll
    for (int ni = 0; ni < 4; ni++) {
      f32x4 v = acc[mi][ni];
      const int m0 = mtile * 256 + wm * 128 + mi * 16 + g * 4;
      const int n = ntile * 256 + wn * 64 + ni * 16 + l15;
      const int b = (n >= 15360) ? 1 : 0;
      const int rem = n - b * 15360;
#pragma unroll
      for (int r = 0; r < 4; r++) {
        const int m = m0 + r;
        out[(long)b * 7864320 + (long)m * 15360 + rem] = f2h(v[r] + bias[m]);
      }
    }
  }
}

// ---------- 128x128 NT GEMM (2-phase, general purpose) ----------
// EPI: 0 f16 transposed store; 1 f16 row store *scale(+bias); 2 qf fp32;
//      3 final fp32 (/bias2[z*5120+n]); 4 fp32 partial row; 5 fp32 transposed
//      partial; 6 f16 partial row; 7 f16 exp row store + row-sum partials
//      (out1 = PSUM[z][m][ntile]); 8 f16 transposed partial
template <int BMODE, int EPI, int SPLITK>
__global__ __launch_bounds__(256, 2)
void gemm_nt(const u16* __restrict__ A, long Azoff, int Astride,
             const u16* __restrict__ B, long Bzoff, int Bstride,
             int K, float scale,
             const float* __restrict__ bias, const float* __restrict__ bias2,
             void* __restrict__ out0, void* __restrict__ out1,
             long out_zoff, int ldo, float cexp = 0.f) {
  __shared__ u16 lds[4 * 8192];
  const int tid = threadIdx.x;
  const int lane = tid & 63;
  const int wave = tid >> 6;
  const int mtile = blockIdx.y, ntile = blockIdx.x, z = blockIdx.z;

  const int zb = (SPLITK > 1) ? z / SPLITK : z;
  const int zc = (SPLITK > 1) ? z % SPLITK : 0;
  const u16* Ab = A + (long)zb * Azoff + (long)zc * K;
  const u16* Bb = B + (long)zb * Bzoff + ((BMODE == 0) ? (long)zc * K : 0);

  const int r8 = lane >> 3;
  const int sphys = lane & 7;
  const u16* aSrc[4];
  const u16* bSrc[4];
  u16* aDst[4];
  u16* bDst[4];
#pragma unroll
  for (int i = 0; i < 4; i++) {
    const int row = wave * 32 + i * 8 + r8;
    const int slog = sphys ^ (row & 7);
    aSrc[i] = Ab + (long)(mtile * 128 + row) * Astride + slog * 8;
    if (BMODE == 0) {
      bSrc[i] = Bb + (long)(ntile * 128 + row) * Bstride + slog * 8;
    } else {
      const int n = ntile * 128 + row;
      const int img = n >> 10;
      const int p = n & 1023;
      const int y = p >> 5, x = p & 31;
      bSrc[i] = Bb + ((long)(img * 34 + y) * 34 + x) * 1024 + slog * 8;
    }
    aDst[i] = &lds[0] + (wave * 32 + i * 8) * 64;
    bDst[i] = &lds[0] + 8192 + (wave * 32 + i * 8) * 64;
  }

  const int g = lane >> 4, l15 = lane & 15;
  const int wm = wave >> 1, wn = wave & 1;
  int offA[2][4], offB[2][4];
#pragma unroll
  for (int ks = 0; ks < 2; ks++) {
    const int sl = ks * 4 + g;
#pragma unroll
    for (int i = 0; i < 4; i++) {
      const int ra = wm * 64 + i * 16 + l15;
      offA[ks][i] = ra * 64 + ((sl ^ (ra & 7)) * 8);
      const int rb = wn * 64 + i * 16 + l15;
      offB[ks][i] = 8192 + rb * 64 + ((sl ^ (rb & 7)) * 8);
    }
  }

  auto stage = [&](int buf, int kb) {
    int bAdd;
    if (BMODE == 0) {
      bAdd = kb;
    } else if (BMODE == 1) {
      const int ktg = (zc * K + kb) >> 6;
      const int cblk = ktg / 9;
      const int t = ktg - cblk * 9;
      const int dy = t / 3, dx = t - dy * 3;
      bAdd = (dy * 34 + dx) * 1024 + cblk * 64;
    } else {
      bAdd = 35 * 1024 + kb;
    }
    const int bufo = buf * 16384;
#pragma unroll
    for (int i = 0; i < 4; i++) gll16(aSrc[i] + kb, aDst[i] + bufo);
#pragma unroll
    for (int i = 0; i < 4; i++) gll16(bSrc[i] + bAdd, bDst[i] + bufo);
  };

  f32x4 acc[4][4];
  const f32x4 zero = {0.f, 0.f, 0.f, 0.f};
#pragma unroll
  for (int i = 0; i < 4; i++)
#pragma unroll
    for (int j = 0; j < 4; j++) acc[i][j] = zero;

  const int nkt = K >> 6;
  stage(0, 0);
  __syncthreads();
  for (int kt = 0; kt < nkt; ++kt) {
    const int buf = kt & 1;
    if (kt + 1 < nkt) stage(buf ^ 1, (kt + 1) << 6);
#pragma unroll
    for (int ks = 0; ks < 2; ks++) {
      f16x8 af[4], bfg[4];
#pragma unroll
      for (int i = 0; i < 4; i++)
        af[i] = *(const f16x8*)&lds[buf * 16384 + offA[ks][i]];
#pragma unroll
      for (int i = 0; i < 4; i++)
        bfg[i] = *(const f16x8*)&lds[buf * 16384 + offB[ks][i]];
#pragma unroll
      for (int mi = 0; mi < 4; mi++)
#pragma unroll
        for (int ni = 0; ni < 4; ni++)
          acc[mi][ni] = __builtin_amdgcn_mfma_f32_16x16x32_f16(
              af[mi], bfg[ni], acc[mi][ni], 0, 0, 0);
    }
    __syncthreads();
  }

  float rp[4][4];
  if (EPI == 7) {
#pragma unroll
    for (int a = 0; a < 4; a++)
#pragma unroll
      for (int b = 0; b < 4; b++) rp[a][b] = 0.f;
  }

#pragma unroll
  for (int mi = 0; mi < 4; mi++) {
#pragma unroll
    for (int ni = 0; ni < 4; ni++) {
      f32x4 v = acc[mi][ni];
      const int m0 = mtile * 128 + wm * 64 + mi * 16 + g * 4;
      const int n = ntile * 128 + wn * 64 + ni * 16 + l15;
      if (EPI == 0) {
        u16* ob = (u16*)out0;
        const float* bs = bias;
        int mm = m0;
        if (out1 != nullptr && m0 >= 128) { ob = (u16*)out1; bs = bias2; mm = m0 - 128; }
        u16x4 pk;
#pragma unroll
        for (int r = 0; r < 4; r++) {
          float val = v[r] * scale + (bs ? bs[mm + r] : 0.f);
          pk[r] = f2h(val);
        }
        *(u16x4*)&ob[(long)n * ldo + mm] = pk;
      } else if (EPI == 1) {
        u16* ob = (u16*)out0 + (long)z * out_zoff;
#pragma unroll
        for (int r = 0; r < 4; r++) {
          const int m = m0 + r;
          float val = v[r] * scale + (bias ? bias[m] : 0.f);
          ob[(long)m * ldo + n] = f2h(val);
        }
      } else if (EPI == 2) {
        float* of = (float*)out0;
        const int img = n >> 10, p = n & 1023;
#pragma unroll
        for (int r = 0; r < 4; r++) {
          const int m = m0 + r;
          of[(long)img * 1048576 + (long)(512 + m) * 1024 + p] =
              v[r] + (bias ? bias[m] : 0.f);
        }
      } else if (EPI == 3) {
        float* of = (float*)out0;
        const int f = n >> 10, p = n & 1023;
        const float dinv = 1.0f / bias2[(long)z * 5120 + n];
#pragma unroll
        for (int r = 0; r < 4; r++) {
          const int m = m0 + r;
          of[(long)z * 5242880 + (long)f * 1048576 + (long)m * 1024 + p] =
              v[r] * dinv;
        }
      } else if (EPI == 4) {
        float* of = (float*)out0 + (long)z * out_zoff;
#pragma unroll
        for (int r = 0; r < 4; r++) of[(long)(m0 + r) * ldo + n] = v[r];
      } else if (EPI == 5) {
        float* of = (float*)out0 + (long)zc * out_zoff;
        *(f32x4*)&of[(long)n * ldo + m0] = v;
      } else if (EPI == 6) {
        u16* ob = (u16*)out0 + (long)z * out_zoff;
#pragma unroll
        for (int r = 0; r < 4; r++) ob[(long)(m0 + r) * ldo + n] = f2h(v[r]);
      } else if (EPI == 7) {
        u16* ob = (u16*)out0 + (long)z * out_zoff;
#pragma unroll
        for (int r = 0; r < 4; r++) {
          const int m = m0 + r;
          float e = __expf(v[r] * scale - cexp);
          ob[(long)m * ldo + n] = f2h(e);
          rp[mi][r] += e;
        }
      } else {  // EPI == 8: f16 transposed partial store
        u16* ob = (u16*)out0 + (long)zc * out_zoff;
        u16x4 pk;
#pragma unroll
        for (int r = 0; r < 4; r++) pk[r] = f2h(v[r]);
        *(u16x4*)&ob[(long)n * ldo + m0] = pk;
      }
    }
  }

  if (EPI == 7) {
    // per-block row-sum partials -> out1 PSUM[(z*MR + m) * NT + ntile]
    float* ps = (float*)lds;  // LDS free after main loop's final barrier
#pragma unroll
    for (int mi = 0; mi < 4; mi++) {
#pragma unroll
      for (int r = 0; r < 4; r++) {
        float s = rp[mi][r];
        s += __shfl_xor(s, 1, 64);
        s += __shfl_xor(s, 2, 64);
        s += __shfl_xor(s, 4, 64);
        s += __shfl_xor(s, 8, 64);
        if (l15 == 0) ps[wn * 128 + wm * 64 + mi * 16 + g * 4 + r] = s;
      }
    }
    __syncthreads();
    if (tid < 128) {
      float s = ps[tid] + ps[128 + tid];
      const int MR = gridDim.y << 7;
      float* PS = (float*)out1;
      PS[((long)z * MR + mtile * 128 + tid) * gridDim.x + ntile] = s;
    }
  }
}

// ---------- launch ----------
extern "C" void kernel_launch(void* const* d_in, const int* in_sizes, int n_in,
                              void* d_out, int out_size, void* d_ws, size_t ws_size,
                              hipStream_t stream) {
  (void)in_sizes; (void)n_in; (void)out_size;
  const float* query   = (const float*)d_in[0];
  const float* support = (const float*)d_in[1];
  const float* w_sk = (const float*)d_in[2];  const float* b_sk = (const float*)d_in[3];
  const float* w_sv = (const float*)d_in[4];  const float* b_sv = (const float*)d_in[5];
  const float* w_qq = (const float*)d_in[6];  const float* b_qq = (const float*)d_in[7];
  const float* w_qk = (const float*)d_in[8];  const float* b_qk = (const float*)d_in[9];
  const float* w_cq = (const float*)d_in[10]; const float* b_cq = (const float*)d_in[11];
  float* out = (float*)d_out;
  char* ws = (char*)d_ws;

  if (ws_size < 158924800u) return;

  u16* PQ    = (u16*)(ws + 0);
  u16* PS    = (u16*)(ws + 23674880);
  u16* WTSK  = (u16*)(ws + 94699520);
  u16* WTSV  = (u16*)(ws + 97058816);
  u16* WTQQK = (u16*)(ws + 106496000);
  u16* WCQ   = (u16*)(ws + 111214592);
  u16* SKR   = (u16*)(ws + 112263168);
  u16* SVA   = (u16*)(ws + 120127488);
  u16* QQR   = (u16*)(ws + 151584768);
  u16* QKR   = (u16*)(ws + 154206208);
  u16* NEWV  = (u16*)(ws + 156827648);
  u16* P1T   = PS;                       // alias (PS dead after sv conv)
  u16* P2T   = PQ;                       // alias (PQ dead after qqk/qf convs)
  u16* PART2 = (u16*)(ws + 94699520);    // over weights: [16][512][1024] f16
  u16* PARTKH = SVA;                     // [2][30720][128] f16 (pre-sv)
  u16* PARTQH = SVA;                     // [2][10240][256] f16 (pre-sv)
  float* PSUM1 = (float*)(ws + 97058816); // over WTSV (dead after sv): 983KB
  float* PSUM2 = (float*)(ws + 94699520); // over PART2 (dead after reduce8h)
  float* D1 = (float*)(ws + 112263168);  // over SKR (dead after P1 gemm)
  float* D2 = D1 + 2048;

  const float SCALE = 0.08838834764831843f;  // 1/sqrt(128)

  pad_both<<<dim3(1280), 256, 0, stream>>>(query, support, PQ, PS);
  wprep<<<dim3(1408), 256, 0, stream>>>(w_sk, w_sv, w_qq, w_qk, w_cq,
                                        WTSK, WTSV, WTQQK, WCQ);

  // sk conv: split-K=2 -> f16 partials, then reduce(+bias)
  gemm_nt<1, 8, 2><<<dim3(240, 1, 2), 256, 0, stream>>>(
      WTSK, 0, 9216, PS, 0, 0, 4608, 1.0f, nullptr, nullptr, PARTKH, nullptr,
      3932160L, 128);
  reduce_sk<<<dim3(3840), 256, 0, stream>>>(PARTKH, b_sk, SKR);

  // qq+qk conv: split-K=2 -> f16 partials, then reduce(+bias)
  gemm_nt<1, 8, 2><<<dim3(80, 2, 2), 256, 0, stream>>>(
      WTQQK, 0, 9216, PQ, 0, 0, 4608, 1.0f, nullptr, nullptr, PARTQH, nullptr,
      2621440L, 256);
  reduce_qqk<<<dim3(2560), 256, 0, stream>>>(PARTQH, b_qq, b_qk, QQR, QKR);

  // sv conv
  gemm256<<<dim3(120, 2), 512, 0, stream>>>(WTSV, PS, b_sv, SVA);

  // qf 1x1 conv
  gemm_nt<2, 2, 1><<<dim3(80, 4, 1), 256, 0, stream>>>(
      WCQ, 0, 1024, PQ, 0, 0, 1024, 1.0f, b_cq, nullptr, out, nullptr, 0, 0);

  // stage 1: P1hat = exp(QK/sqrt(d) - 12) + fused row-sum partials -> D1
  gemm_nt<0, 7, 1><<<dim3(120, 8, 2), 256, 0, stream>>>(
      QQR + 262144, 655360L, 128, SKR, 1966080L, 128, 128, SCALE, nullptr,
      nullptr, P1T, PSUM1, 15728640L, 15360, 12.0f);
  reduceD<<<dim3(2048), 64, 0, stream>>>(PSUM1, D1, 120);
  gemm_nt<0, 6, 8><<<dim3(8, 4, 16), 256, 0, stream>>>(
      SVA, 7864320L, 15360, P1T, 15728640L, 15360, 1920, 1.0f, nullptr,
      nullptr, PART2, nullptr, 524288L, 1024);
  reduce8h<<<dim3(1024), 256, 0, stream>>>(PART2, D1, NEWV);

  // stage 2: P2hat = exp(QK/sqrt(d) - 10) + fused row-sum partials -> D2
  gemm_nt<0, 7, 1><<<dim3(8, 40, 2), 256, 0, stream>>>(
      QQR, 655360L, 128, QKR + 262144, 655360L, 128, 128, SCALE, nullptr,
      nullptr, P2T, PSUM2, 5242880L, 1024, 10.0f);
  reduceD<<<dim3(10240), 64, 0, stream>>>(PSUM2, D2, 8);
  gemm_nt<0, 3, 1><<<dim3(40, 4, 2), 256, 0, stream>>>(
      NEWV, 524288L, 1024, P2T, 5242880L, 1024, 1024, 1.0f, nullptr, D2,
      out, nullptr, 0, 0);
}

// Round 14
// 581.356 us; speedup vs baseline: 1.4303x; 1.0243x over previous
//
#include <hip/hip_runtime.h>
#include <cstdint>

typedef unsigned short u16;
typedef __attribute__((ext_vector_type(8))) u16 u16x8;
typedef __attribute__((ext_vector_type(4))) u16 u16x4;
typedef __attribute__((ext_vector_type(8))) _Float16 f16x8;
typedef __attribute__((ext_vector_type(4))) float f32x4;

// ---------- helpers ----------
__device__ __forceinline__ u16 f2h(float f) {
  _Float16 h = (_Float16)f;
  return __builtin_bit_cast(u16, h);
}
__device__ __forceinline__ float h2f(u16 b) {
  _Float16 h = __builtin_bit_cast(_Float16, b);
  return (float)h;
}
__device__ __forceinline__ void gll16(const void* g, void* l) {
  auto gp = reinterpret_cast<const __attribute__((address_space(1))) unsigned int*>(
      reinterpret_cast<uintptr_t>(g));
  auto lp = reinterpret_cast<__attribute__((address_space(3))) unsigned int*>(
      reinterpret_cast<uintptr_t>(l));
  __builtin_amdgcn_global_load_lds(gp, lp, 16, 0, 0);
}

// ---------- merged prep: pad (blocks 0-1279) + weight reshape (1280-2687) ----
__device__ __forceinline__ void wre3_body(const float* __restrict__ wp,
                                          u16* __restrict__ op, float* buf) {
  for (int i = threadIdx.x; i < 9216; i += 256) buf[i] = wp[i];
  __syncthreads();
  for (int k = threadIdx.x; k < 9216; k += 256) {
    const int cblk = k / 576;
    const int r = k - cblk * 576;
    const int t = r >> 6, ci = r & 63;
    op[k] = f2h(buf[(cblk * 64 + ci) * 9 + t]);
  }
}
__global__ __launch_bounds__(256) void prep_all(
    const float* __restrict__ qsrc, const float* __restrict__ ssrc,
    u16* __restrict__ PQ, u16* __restrict__ PS,
    const float* __restrict__ w_sk, const float* __restrict__ w_sv,
    const float* __restrict__ w_qq, const float* __restrict__ w_qk,
    const float* __restrict__ w_cq, u16* __restrict__ WTSK,
    u16* __restrict__ WTSV, u16* __restrict__ WTQQK, u16* __restrict__ WCQ) {
  __shared__ float buf[9216];
  const int bb = blockIdx.x;
  if (bb < 1280) {
    const int gi = bb >> 5;
    const int y  = bb & 31;
    const float* in;
    u16* outp;
    int img;
    if (gi < 10) { in = qsrc; outp = PQ; img = gi; }
    else         { in = ssrc; outp = PS; img = gi - 10; }
    float (*tile)[33] = (float(*)[33])buf;
    const int tid = threadIdx.x;
    u16* base = outp + (long)img * 34 * 34 * 1024;
    const u16x8 z8 = {0, 0, 0, 0, 0, 0, 0, 0};
    {
      u16* r = base + (long)(y + 1) * 34 * 1024;
      if (tid < 128) *(u16x8*)&r[tid * 8] = z8;
      else *(u16x8*)&r[33 * 1024 + (tid - 128) * 8] = z8;
    }
    if (y == 0) {
      for (int i = tid * 8; i < 34816; i += 2048) *(u16x8*)&base[i] = z8;
    }
    if (y == 31) {
      u16* r = base + 33L * 34 * 1024;
      for (int i = tid * 8; i < 34816; i += 2048) *(u16x8*)&r[i] = z8;
    }
    const int xi = tid & 31, ci = tid >> 5;
    const int xo = tid >> 3, q = tid & 7;
    const float* ip = in + (long)img * 1048576 + y * 32;
    u16* op = base + ((long)(y + 1) * 34 + 1) * 1024;
    for (int c0 = 0; c0 < 1024; c0 += 32) {
#pragma unroll
      for (int k2 = 0; k2 < 4; k2++)
        tile[k2 * 8 + ci][xi] = ip[(long)(c0 + k2 * 8 + ci) * 1024 + xi];
      __syncthreads();
      u16x4 o4;
#pragma unroll
      for (int r = 0; r < 4; r++) o4[r] = f2h(tile[q * 4 + r][xo]);
      *(u16x4*)&op[(long)xo * 1024 + c0 + q * 4] = o4;
      __syncthreads();
    }
  } else {
    const int b = bb - 1280;
    if (b < 128) {
      wre3_body(w_sk + (long)b * 9216, WTSK + (long)b * 9216, buf);
    } else if (b < 640) {
      const int oc = b - 128;
      wre3_body(w_sv + (long)oc * 9216, WTSV + (long)oc * 9216, buf);
    } else if (b < 768) {
      const int oc = b - 640;
      wre3_body(w_qq + (long)oc * 9216, WTQQK + (long)oc * 9216, buf);
    } else if (b < 896) {
      const int oc = b - 768;
      wre3_body(w_qk + (long)oc * 9216, WTQQK + (long)(oc + 128) * 9216, buf);
    } else {
      const int i = (b - 896) * 1024 + threadIdx.x * 4;
#pragma unroll
      for (int r = 0; r < 4; r++) WCQ[i + r] = f2h(w_cq[i + r]);
    }
  }
}

// ---------- merged D reduces: rows 0-2047 -> D1 (NT=120), rest -> D2 (NT=8) --
__global__ __launch_bounds__(64) void reduceDx(const float* __restrict__ ps1,
                                               float* __restrict__ D1,
                                               const float* __restrict__ ps2,
                                               float* __restrict__ D2) {
  const int row = blockIdx.x, tid = threadIdx.x;
  const float* p;
  float* D;
  int NT;
  if (row < 2048) { p = ps1 + (long)row * 120; D = D1 + row; NT = 120; }
  else { const int r2 = row - 2048; p = ps2 + (long)r2 * 8; D = D2 + r2; NT = 8; }
  float s = (tid < NT) ? p[tid] : 0.f;
  if (tid + 64 < NT) s += p[tid + 64];
#pragma unroll
  for (int o = 32; o > 0; o >>= 1) s += __shfl_xor(s, o, 64);
  if (tid == 0) *D = s;
}

// ---------- split-K reducers ----------
__global__ __launch_bounds__(256) void reduce8h(const u16* __restrict__ part,
                                                const float* __restrict__ D,
                                                u16* __restrict__ o) {
  long j = ((long)blockIdx.x * 256 + threadIdx.x) * 4;
  int b = (int)(j >> 19);
  long i = j & 524287;
  int q = (int)(i & 1023);
  const u16* p = part + (long)b * 4194304 + i;
  float s0 = 0.f, s1 = 0.f, s2 = 0.f, s3 = 0.f;
#pragma unroll
  for (int c = 0; c < 8; c++) {
    u16x4 v = *(const u16x4*)&p[(long)c * 524288];
    s0 += h2f(v[0]); s1 += h2f(v[1]); s2 += h2f(v[2]); s3 += h2f(v[3]);
  }
  f32x4 dv = *(const f32x4*)&D[b * 1024 + q];
  u16x4 o4 = {f2h(s0 / dv[0]), f2h(s1 / dv[1]), f2h(s2 / dv[2]),
              f2h(s3 / dv[3])};
  *(u16x4*)&o[j] = o4;
}
// merged: blocks 0-3839 sk-reduce, 3840-6399 qqk-reduce
__global__ __launch_bounds__(256) void reduce_kq(
    const u16* __restrict__ partK, const float* __restrict__ b_sk,
    u16* __restrict__ SKR, const u16* __restrict__ partQ,
    const float* __restrict__ b_qq, const float* __restrict__ b_qk,
    u16* __restrict__ QQR, u16* __restrict__ QKR) {
  int blk = blockIdx.x;
  if (blk < 3840) {
    long i = ((long)blk * 256 + threadIdx.x) * 4;
    u16x4 a = *(const u16x4*)&partK[i];
    u16x4 b = *(const u16x4*)&partK[i + 3932160];
    f32x4 bb = *(const f32x4*)&b_sk[(int)(i & 127)];
    u16x4 o4;
#pragma unroll
    for (int r = 0; r < 4; r++) o4[r] = f2h(h2f(a[r]) + h2f(b[r]) + bb[r]);
    *(u16x4*)&SKR[i] = o4;
  } else {
    blk -= 3840;
    long i = ((long)blk * 256 + threadIdx.x) * 4;
    const int n = (int)(i >> 8), m = (int)(i & 255);
    u16x4 a = *(const u16x4*)&partQ[i];
    u16x4 b = *(const u16x4*)&partQ[i + 2621440];
    const int lo = (m < 128);
    const int mm = m & 127;
    const float* bs = lo ? b_qq : b_qk;
    f32x4 bb = *(const f32x4*)&bs[mm];
    u16* dst = (lo ? QQR : QKR) + (long)n * 128 + mm;
    u16x4 o4;
#pragma unroll
    for (int r = 0; r < 4; r++) o4[r] = f2h(h2f(a[r]) + h2f(b[r]) + bb[r]);
    *(u16x4*)dst = o4;
  }
}

// ---------- 256x256 GEMM, barrier-free K-tile interior (r8/r10 proven) ----
__global__ __launch_bounds__(512, 1)
void gemm256(const u16* __restrict__ A, const u16* __restrict__ B,
             const float* __restrict__ bias, u16* __restrict__ out) {
  __shared__ u16 lds[81920];  // A: 2x32KB @0, B: 3x32KB @32768(u16)
  const int tid = threadIdx.x, lane = tid & 63, wave = tid >> 6;
  const int nwg = gridDim.x * gridDim.y;
  int wg = blockIdx.x + gridDim.x * blockIdx.y;
  wg = (wg & 7) * (nwg >> 3) + (wg >> 3);
  const int ntile = wg % gridDim.x;
  const int mtile = wg / gridDim.x;

  const int slog = (lane & 7) ^ ((lane >> 3) & 7);
  const u16* aS[4];
  const u16* bS[4];
  int aD[4], bD[4];
#pragma unroll
  for (int j = 0; j < 4; j++) {
    const int r = wave * 32 + j * 8 + (lane >> 3);
    aS[j] = A + (long)(mtile * 256 + r) * 9216 + slog * 8;
    aD[j] = (wave * 32 + j * 8) * 64;
    const int n = ntile * 256 + r;
    const int img = n >> 10, p = n & 1023;
    const int y = p >> 5, x = p & 31;
    bS[j] = B + ((long)((img * 34 + y) * 34 + x)) * 1024 + slog * 8;
    bD[j] = (wave * 32 + j * 8) * 64;
  }

  const int g = lane >> 4, l15 = lane & 15;
  const int wm = wave >> 2, wn = wave & 3;
  int aRow[8], bRow[4], sx[2];
#pragma unroll
  for (int mi = 0; mi < 8; mi++) aRow[mi] = (wm * 128 + mi * 16 + l15) * 64;
#pragma unroll
  for (int ni = 0; ni < 4; ni++) bRow[ni] = (wn * 64 + ni * 16 + l15) * 64;
#pragma unroll
  for (int ks = 0; ks < 2; ks++) sx[ks] = ((ks * 4 + g) ^ (l15 & 7)) * 8;

  auto conv_badd = [](int kt) {
    const int cblk = kt / 9;
    const int t = kt - cblk * 9;
    const int dy = t / 3, dx = t - dy * 3;
    return (dy * 34 + dx) * 1024 + cblk * 64;
  };

  f32x4 acc[8][4];
  const f32x4 zero = {0.f, 0.f, 0.f, 0.f};
#pragma unroll
  for (int i = 0; i < 8; i++)
#pragma unroll
    for (int j = 0; j < 4; j++) acc[i][j] = zero;

  const int nkt = 144;
  {
#pragma unroll
    for (int j = 0; j < 4; j++) gll16(aS[j], &lds[aD[j]]);
    const int b0o = conv_badd(0), b1o = conv_badd(1);
#pragma unroll
    for (int j = 0; j < 4; j++) gll16(bS[j] + b0o, &lds[32768 + bD[j]]);
#pragma unroll
    for (int j = 0; j < 4; j++) gll16(bS[j] + b1o, &lds[49152 + bD[j]]);
    asm volatile("s_waitcnt vmcnt(4)" ::: "memory");
    __builtin_amdgcn_s_barrier();
  }

  f16x8 a0[4], a1[4], a3[4], b0[4], b2[4];
  f16x8 zf;
#pragma unroll
  for (int j = 0; j < 8; j++) zf[j] = (_Float16)0.0f;
#pragma unroll
  for (int i = 0; i < 4; i++) { a3[i] = zf; b2[i] = zf; }

  int bc = 0;
  for (int kt = 0; kt < nkt; ++kt) {
    const int abuf = (kt & 1) << 14;
    const int anbuf = abuf ^ 16384;
    const int bbuf = 32768 + bc * 16384;
    int bsn = bc + 2; if (bsn >= 3) bsn -= 3;
    const int bnbuf = 32768 + bsn * 16384;
    const bool stA = (kt + 1 < nkt);
    const bool stB = (kt + 2 < nkt);
    const int kA = (kt + 1) << 6;
    const int bAdd2 = stB ? conv_badd(kt + 2) : 0;

#pragma unroll
    for (int i = 0; i < 4; i++) a0[i] = *(const f16x8*)&lds[abuf + aRow[i] + sx[0]];
#pragma unroll
    for (int i = 0; i < 4; i++) b0[i] = *(const f16x8*)&lds[bbuf + bRow[i] + sx[0]];
#pragma unroll
    for (int i = 0; i < 4; i++) a1[i] = *(const f16x8*)&lds[abuf + aRow[i + 4] + sx[0]];
#pragma unroll
    for (int mi = 0; mi < 4; mi++)
#pragma unroll
      for (int ni = 0; ni < 4; ni++)
        acc[mi + 4][ni] = __builtin_amdgcn_mfma_f32_16x16x32_f16(
            a3[mi], b2[ni], acc[mi + 4][ni], 0, 0, 0);
    if (stA) {
#pragma unroll
      for (int j = 0; j < 4; j++) gll16(aS[j] + kA, &lds[anbuf + aD[j]]);
    }
#pragma unroll
    for (int mi = 0; mi < 4; mi++)
#pragma unroll
      for (int ni = 0; ni < 4; ni++)
        acc[mi][ni] = __builtin_amdgcn_mfma_f32_16x16x32_f16(
            a0[mi], b0[ni], acc[mi][ni], 0, 0, 0);
#pragma unroll
    for (int i = 0; i < 4; i++) a0[i] = *(const f16x8*)&lds[abuf + aRow[i] + sx[1]];
#pragma unroll
    for (int i = 0; i < 4; i++) b2[i] = *(const f16x8*)&lds[bbuf + bRow[i] + sx[1]];
    if (stB) {
#pragma unroll
      for (int j = 0; j < 4; j++) gll16(bS[j] + bAdd2, &lds[bnbuf + bD[j]]);
    }
#pragma unroll
    for (int mi = 0; mi < 4; mi++)
#pragma unroll
      for (int ni = 0; ni < 4; ni++)
        acc[mi + 4][ni] = __builtin_amdgcn_mfma_f32_16x16x32_f16(
            a1[mi], b0[ni], acc[mi + 4][ni], 0, 0, 0);
#pragma unroll
    for (int i = 0; i < 4; i++) a3[i] = *(const f16x8*)&lds[abuf + aRow[i + 4] + sx[1]];
#pragma unroll
    for (int mi = 0; mi < 4; mi++)
#pragma unroll
      for (int ni = 0; ni < 4; ni++)
        acc[mi][ni] = __builtin_amdgcn_mfma_f32_16x16x32_f16(
            a0[mi], b2[ni], acc[mi][ni], 0, 0, 0);
    if (stB) {
      asm volatile("s_waitcnt vmcnt(4)" ::: "memory");
    } else if (stA) {
      asm volatile("s_waitcnt vmcnt(0)" ::: "memory");
    }
    __builtin_amdgcn_s_barrier();
    bc = bc + 1; if (bc >= 3) bc -= 3;
  }
#pragma unroll
  for (int mi = 0; mi < 4; mi++)
#pragma unroll
    for (int ni = 0; ni < 4; ni++)
      acc[mi + 4][ni] = __builtin_amdgcn_mfma_f32_16x16x32_f16(
          a3[mi], b2[ni], acc[mi + 4][ni], 0, 0, 0);

#pragma unroll
  for (int mi = 0; mi < 8; mi++) {
#pragma unroll
    for (int ni = 0; ni < 4; ni++) {
      f32x4 v = acc[mi][ni];
      const int m0 = mtile * 256 + wm * 128 + mi * 16 + g * 4;
      const int n = ntile * 256 + wn * 64 + ni * 16 + l15;
      const int b = (n >= 15360) ? 1 : 0;
      const int rem = n - b * 15360;
#pragma unroll
      for (int r = 0; r < 4; r++) {
        const int m = m0 + r;
        out[(long)b * 7864320 + (long)m * 15360 + rem] = f2h(v[r] + bias[m]);
      }
    }
  }
}

// ---------- 128x128 NT GEMM body (shared) ----------
// EPI: 2 qf fp32; 3 final fp32 (/bias2[z*5120+n]); 6 f16 partial row;
//      7 f16 exp row store + row-sum partials; 8 f16 transposed partial
template <int BMODE, int EPI, int SPLITK>
__device__ __forceinline__ void gemm_body(
    int mtile, int ntile, int z, int NTd, int MRd,
    const u16* __restrict__ A, long Azoff, int Astride,
    const u16* __restrict__ B, long Bzoff, int Bstride,
    int K, float scale, const float* __restrict__ bias,
    const float* __restrict__ bias2, void* __restrict__ out0,
    void* __restrict__ out1, long out_zoff, int ldo, float cexp, u16* lds) {
  const int tid = threadIdx.x;
  const int lane = tid & 63;
  const int wave = tid >> 6;

  const int zb = (SPLITK > 1) ? z / SPLITK : z;
  const int zc = (SPLITK > 1) ? z % SPLITK : 0;
  const u16* Ab = A + (long)zb * Azoff + (long)zc * K;
  const u16* Bb = B + (long)zb * Bzoff + ((BMODE == 0) ? (long)zc * K : 0);

  const int r8 = lane >> 3;
  const int sphys = lane & 7;
  const u16* aSrc[4];
  const u16* bSrc[4];
  u16* aDst[4];
  u16* bDst[4];
#pragma unroll
  for (int i = 0; i < 4; i++) {
    const int row = wave * 32 + i * 8 + r8;
    const int slog = sphys ^ (row & 7);
    aSrc[i] = Ab + (long)(mtile * 128 + row) * Astride + slog * 8;
    if (BMODE == 0) {
      bSrc[i] = Bb + (long)(ntile * 128 + row) * Bstride + slog * 8;
    } else {
      const int n = ntile * 128 + row;
      const int img = n >> 10;
      const int p = n & 1023;
      const int y = p >> 5, x = p & 31;
      bSrc[i] = Bb + ((long)(img * 34 + y) * 34 + x) * 1024 + slog * 8;
    }
    aDst[i] = lds + (wave * 32 + i * 8) * 64;
    bDst[i] = lds + 8192 + (wave * 32 + i * 8) * 64;
  }

  const int g = lane >> 4, l15 = lane & 15;
  const int wm = wave >> 1, wn = wave & 1;
  int offA[2][4], offB[2][4];
#pragma unroll
  for (int ks = 0; ks < 2; ks++) {
    const int sl = ks * 4 + g;
#pragma unroll
    for (int i = 0; i < 4; i++) {
      const int ra = wm * 64 + i * 16 + l15;
      offA[ks][i] = ra * 64 + ((sl ^ (ra & 7)) * 8);
      const int rb = wn * 64 + i * 16 + l15;
      offB[ks][i] = 8192 + rb * 64 + ((sl ^ (rb & 7)) * 8);
    }
  }

  auto stage = [&](int buf, int kb) {
    int bAdd;
    if (BMODE == 0) {
      bAdd = kb;
    } else if (BMODE == 1) {
      const int ktg = (zc * K + kb) >> 6;
      const int cblk = ktg / 9;
      const int t = ktg - cblk * 9;
      const int dy = t / 3, dx = t - dy * 3;
      bAdd = (dy * 34 + dx) * 1024 + cblk * 64;
    } else {
      bAdd = 35 * 1024 + kb;
    }
    const int bufo = buf * 16384;
#pragma unroll
    for (int i = 0; i < 4; i++) gll16(aSrc[i] + kb, aDst[i] + bufo);
#pragma unroll
    for (int i = 0; i < 4; i++) gll16(bSrc[i] + bAdd, bDst[i] + bufo);
  };

  f32x4 acc[4][4];
  const f32x4 zero = {0.f, 0.f, 0.f, 0.f};
#pragma unroll
  for (int i = 0; i < 4; i++)
#pragma unroll
    for (int j = 0; j < 4; j++) acc[i][j] = zero;

  const int nkt = K >> 6;
  stage(0, 0);
  __syncthreads();
  for (int kt = 0; kt < nkt; ++kt) {
    const int buf = kt & 1;
    if (kt + 1 < nkt) stage(buf ^ 1, (kt + 1) << 6);
#pragma unroll
    for (int ks = 0; ks < 2; ks++) {
      f16x8 af[4], bfg[4];
#pragma unroll
      for (int i = 0; i < 4; i++)
        af[i] = *(const f16x8*)&lds[buf * 16384 + offA[ks][i]];
#pragma unroll
      for (int i = 0; i < 4; i++)
        bfg[i] = *(const f16x8*)&lds[buf * 16384 + offB[ks][i]];
#pragma unroll
      for (int mi = 0; mi < 4; mi++)
#pragma unroll
        for (int ni = 0; ni < 4; ni++)
          acc[mi][ni] = __builtin_amdgcn_mfma_f32_16x16x32_f16(
              af[mi], bfg[ni], acc[mi][ni], 0, 0, 0);
    }
    __syncthreads();
  }

  float rp[4][4];
  if (EPI == 7) {
#pragma unroll
    for (int a = 0; a < 4; a++)
#pragma unroll
      for (int b = 0; b < 4; b++) rp[a][b] = 0.f;
  }

#pragma unroll
  for (int mi = 0; mi < 4; mi++) {
#pragma unroll
    for (int ni = 0; ni < 4; ni++) {
      f32x4 v = acc[mi][ni];
      const int m0 = mtile * 128 + wm * 64 + mi * 16 + g * 4;
      const int n = ntile * 128 + wn * 64 + ni * 16 + l15;
      if (EPI == 2) {
        float* of = (float*)out0;
        const int img = n >> 10, p = n & 1023;
#pragma unroll
        for (int r = 0; r < 4; r++) {
          const int m = m0 + r;
          of[(long)img * 1048576 + (long)(512 + m) * 1024 + p] =
              v[r] + (bias ? bias[m] : 0.f);
        }
      } else if (EPI == 3) {
        float* of = (float*)out0;
        const int f = n >> 10, p = n & 1023;
        const float dinv = 1.0f / bias2[(long)z * 5120 + n];
#pragma unroll
        for (int r = 0; r < 4; r++) {
          const int m = m0 + r;
          of[(long)z * 5242880 + (long)f * 1048576 + (long)m * 1024 + p] =
              v[r] * dinv;
        }
      } else if (EPI == 6) {
        u16* ob = (u16*)out0 + (long)z * out_zoff;
#pragma unroll
        for (int r = 0; r < 4; r++) ob[(long)(m0 + r) * ldo + n] = f2h(v[r]);
      } else if (EPI == 7) {
        u16* ob = (u16*)out0 + (long)z * out_zoff;
#pragma unroll
        for (int r = 0; r < 4; r++) {
          const int m = m0 + r;
          float e = __expf(v[r] * scale - cexp);
          ob[(long)m * ldo + n] = f2h(e);
          rp[mi][r] += e;
        }
      } else {  // EPI == 8: f16 transposed partial store
        u16* ob = (u16*)out0 + (long)zc * out_zoff;
        u16x4 pk;
#pragma unroll
        for (int r = 0; r < 4; r++) pk[r] = f2h(v[r]);
        *(u16x4*)&ob[(long)n * ldo + m0] = pk;
      }
    }
  }

  if (EPI == 7) {
    float* ps = (float*)lds;
#pragma unroll
    for (int mi = 0; mi < 4; mi++) {
#pragma unroll
      for (int r = 0; r < 4; r++) {
        float s = rp[mi][r];
        s += __shfl_xor(s, 1, 64);
        s += __shfl_xor(s, 2, 64);
        s += __shfl_xor(s, 4, 64);
        s += __shfl_xor(s, 8, 64);
        if (l15 == 0) ps[wn * 128 + wm * 64 + mi * 16 + g * 4 + r] = s;
      }
    }
    __syncthreads();
    if (tid < 128) {
      float s = ps[tid] + ps[128 + tid];
      float* PSp = (float*)out1;
      PSp[((long)z * MRd + mtile * 128 + tid) * NTd + ntile] = s;
    }
  }
}

template <int BMODE, int EPI, int SPLITK>
__global__ __launch_bounds__(256, 2)
void gemm_nt(const u16* __restrict__ A, long Azoff, int Astride,
             const u16* __restrict__ B, long Bzoff, int Bstride,
             int K, float scale,
             const float* __restrict__ bias, const float* __restrict__ bias2,
             void* __restrict__ out0, void* __restrict__ out1,
             long out_zoff, int ldo, float cexp = 0.f) {
  __shared__ u16 lds[32768];
  gemm_body<BMODE, EPI, SPLITK>(blockIdx.y, blockIdx.x, blockIdx.z,
                                gridDim.x, gridDim.y << 7, A, Azoff, Astride,
                                B, Bzoff, Bstride, K, scale, bias, bias2,
                                out0, out1, out_zoff, ldo, cexp, lds);
}

// ---------- merged sk + qqk convs (blocks 0-479 sk, 480-799 qqk) ----------
__global__ __launch_bounds__(256, 2)
void conv_dual(const u16* __restrict__ WTSK, const u16* __restrict__ WTQQK,
               const u16* __restrict__ PS, const u16* __restrict__ PQ,
               u16* __restrict__ PARTKH, u16* __restrict__ PARTQH) {
  __shared__ u16 lds[32768];
  int b = blockIdx.x;
  if (b < 480) {
    gemm_body<1, 8, 2>(0, b % 240, b / 240, 0, 0, WTSK, 0, 9216, PS, 0, 0,
                       4608, 1.0f, nullptr, nullptr, PARTKH, nullptr,
                       3932160L, 128, 0.f, lds);
  } else {
    b -= 480;
    gemm_body<1, 8, 2>((b / 80) % 2, b % 80, b / 160, 0, 0, WTQQK, 0, 9216,
                       PQ, 0, 0, 4608, 1.0f, nullptr, nullptr, PARTQH,
                       nullptr, 2621440L, 256, 0.f, lds);
  }
}

// ---------- merged P1 + P2 exp-GEMMs (blocks 0-1919 P1, 1920-2559 P2) -----
__global__ __launch_bounds__(256, 2)
void pgemm_dual(const u16* __restrict__ QQR, const u16* __restrict__ SKR,
                const u16* __restrict__ QKR, u16* __restrict__ P1T,
                u16* __restrict__ P2T, float* __restrict__ PSUM1,
                float* __restrict__ PSUM2, float scale) {
  __shared__ u16 lds[32768];
  int b = blockIdx.x;
  if (b < 1920) {
    gemm_body<0, 7, 1>((b / 120) % 8, b % 120, b / 960, 120, 1024,
                       QQR + 262144, 655360L, 128, SKR, 1966080L, 128, 128,
                       scale, nullptr, nullptr, P1T, PSUM1, 15728640L, 15360,
                       12.0f, lds);
  } else {
    b -= 1920;
    gemm_body<0, 7, 1>((b / 8) % 40, b % 8, b / 320, 8, 5120, QQR, 655360L,
                       128, QKR + 262144, 655360L, 128, 128, scale, nullptr,
                       nullptr, P2T, PSUM2, 5242880L, 1024, 10.0f, lds);
  }
}

// ---------- launch ----------
extern "C" void kernel_launch(void* const* d_in, const int* in_sizes, int n_in,
                              void* d_out, int out_size, void* d_ws, size_t ws_size,
                              hipStream_t stream) {
  (void)in_sizes; (void)n_in; (void)out_size;
  const float* query   = (const float*)d_in[0];
  const float* support = (const float*)d_in[1];
  const float* w_sk = (const float*)d_in[2];  const float* b_sk = (const float*)d_in[3];
  const float* w_sv = (const float*)d_in[4];  const float* b_sv = (const float*)d_in[5];
  const float* w_qq = (const float*)d_in[6];  const float* b_qq = (const float*)d_in[7];
  const float* w_qk = (const float*)d_in[8];  const float* b_qk = (const float*)d_in[9];
  const float* w_cq = (const float*)d_in[10]; const float* b_cq = (const float*)d_in[11];
  float* out = (float*)d_out;
  char* ws = (char*)d_ws;

  if (ws_size < 158924800u) return;

  u16* PQ    = (u16*)(ws + 0);
  u16* PS    = (u16*)(ws + 23674880);
  u16* WTSK  = (u16*)(ws + 94699520);
  u16* WTSV  = (u16*)(ws + 97058816);
  u16* WTQQK = (u16*)(ws + 106496000);
  u16* WCQ   = (u16*)(ws + 111214592);
  u16* SKR   = (u16*)(ws + 112263168);
  u16* SVA   = (u16*)(ws + 120127488);
  u16* QQR   = (u16*)(ws + 151584768);
  u16* QKR   = (u16*)(ws + 154206208);
  u16* NEWV  = (u16*)(ws + 156827648);
  u16* P1T   = PS;                        // alias (PS dead after sv conv)
  u16* P2T   = PQ;                        // alias (PQ dead after qqk/qf convs)
  u16* PART2 = (u16*)(ws + 94699520);     // over weights (dead after convs)
  u16* PARTKH = SVA;                      // [2][30720][128] f16 @ SVA+0
  u16* PARTQH = SVA + 7864320;            // [2][10240][256] f16 @ SVA+15.7MB (disjoint!)
  float* PSUM1 = (float*)(ws + 97058816); // over WTSV (dead after gemm256)
  float* PSUM2 = (float*)(ws + 94699520); // over WTSK (dead after conv_dual)
  float* D1 = (float*)(ws + 112263168);   // over SKR (dead after pgemm_dual)
  float* D2 = D1 + 2048;

  const float SCALE = 0.08838834764831843f;  // 1/sqrt(128)

  prep_all<<<dim3(2688), 256, 0, stream>>>(query, support, PQ, PS, w_sk, w_sv,
                                           w_qq, w_qk, w_cq, WTSK, WTSV,
                                           WTQQK, WCQ);

  // sk + qq/qk convs (split-K=2, f16 partials, disjoint partial buffers)
  conv_dual<<<dim3(800), 256, 0, stream>>>(WTSK, WTQQK, PS, PQ, PARTKH, PARTQH);
  reduce_kq<<<dim3(6400), 256, 0, stream>>>(PARTKH, b_sk, SKR, PARTQH, b_qq,
                                            b_qk, QQR, QKR);

  // sv conv (overwrites the partial region -> after reduce_kq)
  gemm256<<<dim3(120, 2), 512, 0, stream>>>(WTSV, PS, b_sv, SVA);

  // qf 1x1 conv
  gemm_nt<2, 2, 1><<<dim3(80, 4, 1), 256, 0, stream>>>(
      WCQ, 0, 1024, PQ, 0, 0, 1024, 1.0f, b_cq, nullptr, out, nullptr, 0, 0);

  // P1 + P2 exp-GEMMs with fused row-sum partials
  pgemm_dual<<<dim3(2560), 256, 0, stream>>>(QQR, SKR, QKR, P1T, P2T, PSUM1,
                                             PSUM2, SCALE);
  reduceDx<<<dim3(12288), 64, 0, stream>>>(PSUM1, D1, PSUM2, D2);

  // newV = SV * P1hat^T (split-K=16, f16 partials) then /D1
  gemm_nt<0, 6, 8><<<dim3(8, 4, 16), 256, 0, stream>>>(
      SVA, 7864320L, 15360, P1T, 15728640L, 15360, 1920, 1.0f, nullptr,
      nullptr, PART2, nullptr, 524288L, 1024);
  reduce8h<<<dim3(1024), 256, 0, stream>>>(PART2, D1, NEWV);

  // Out = newV * P2hat^T / D2
  gemm_nt<0, 3, 1><<<dim3(40, 4, 2), 256, 0, stream>>>(
      NEWV, 524288L, 1024, P2T, 5242880L, 1024, 1024, 1.0f, nullptr, D2,
      out, nullptr, 0, 0);
}